// Round 2
// baseline (442.968 us; speedup 1.0000x reference)
//
#include <hip/hip_runtime.h>
#include <math.h>

#define NB 32
#define NS 4096
#define ND 512
#define NU 128
#define RR 32          // rows of values per block

typedef __bf16 bf16x8 __attribute__((ext_vector_type(8)));
typedef unsigned short u16x8 __attribute__((ext_vector_type(8)));
typedef float f32x4 __attribute__((ext_vector_type(4)));

union FragCvt { u16x8 u; bf16x8 b; };

__device__ inline unsigned short f2bf(float x) {
  union { float f; unsigned u; } v; v.f = x;
  return (unsigned short)((v.u + 0x7FFFu + ((v.u >> 16) & 1u)) >> 16);
}
__device__ inline float fast_tanh(float x) {
  // tanh(x) = (e^{2x}-1)/(e^{2x}+1); clamp so e^{2x} stays finite (tanh saturated anyway)
  x = fminf(9.f, fmaxf(-9.f, x));
  float e2 = __expf(2.f * x);
  return (e2 - 1.f) * __builtin_amdgcn_rcpf(e2 + 1.f);
}

// ---------------- prep: qb[b][u] += partial(query@W1) + b1 + b2 (split-K, qb pre-zeroed) ----------------
__global__ void prep_qb(const float* __restrict__ q, const float* __restrict__ W1,
                        const float* __restrict__ b1, const float* __restrict__ b2,
                        float* __restrict__ qb) {
  const int bb = blockIdx.x >> 4;
  const int kc = blockIdx.x & 15;
  const int u  = threadIdx.x & 127;
  const int dh = threadIdx.x >> 7;
  const int d0 = kc * 32 + dh * 16;
  const float* qr = q + bb * ND + d0;
  const float* w  = W1 + (size_t)d0 * NU + u;
  float s = (kc == 0 && dh == 0) ? (b1[u] + b2[u]) : 0.f;
  #pragma unroll
  for (int j = 0; j < 16; ++j) s += qr[j] * w[j * NU];
  atomicAdd(qb + bb * NU + u, s);
}

// ---------------- prep: W2 -> fragment-major bf16 frags ----------------
// w2f[(kt*8 + ut)*64 + lane] = 8 bf16: rows u=ut*16+(lane&15), cols d=kt*32+(lane>>4)*8 .. +8
__global__ void prep_w2f(const float* __restrict__ W2, uint4* __restrict__ w2f) {
  const int idx = blockIdx.x * 256 + threadIdx.x;   // 8192 frags
  const int lane = idx & 63;
  const int ut   = (idx >> 6) & 7;
  const int kt   = idx >> 9;
  const int lidx = lane & 15;
  const int quad = lane >> 4;
  const int u  = ut * 16 + lidx;
  const int d0 = kt * 32 + quad * 8;
  unsigned short o[8];
  #pragma unroll
  for (int j = 0; j < 8; ++j) o[j] = f2bf(W2[(size_t)(d0 + j) * NU + u]);
  w2f[idx] = *(const uint4*)o;
}

// ---------------- fused: proj -> tanh -> score -> exp -> partial softmax + context ----------------
// Streaming design: NO LDS staging, NO in-loop barriers. A-fragments read straight from
// global fp32 values (per kt the 4 quads consume a full 128B line per row), cvt to bf16
// in-register; B frags stream from L2. Context pass re-reads the L2-hot chunk in fp32.
__global__ __launch_bounds__(256, 4) void fused_attn(
    const float* __restrict__ values,
    const float* __restrict__ qb,            // [NB][NU]
    const uint4* __restrict__ w2f,           // [16][8][64] frags
    const float* __restrict__ V,             // [NU]
    const float* __restrict__ bvp,           // [1]
    float* __restrict__ wout,                // [NB][NS] unnormalized e^s
    float* __restrict__ Cacc,                // [NB][ND] partial context (ws, zeroed)
    float* __restrict__ Lacc)                // [NB] partial denom (ws, zeroed)
{
  __shared__ float sbuf[4][16];
  __shared__ float wlds[RR];

  const int tid = threadIdx.x;
  const int b = blockIdx.x >> 7;        // 128 chunks per batch
  const int chunk = blockIdx.x & 127;
  const int s0 = chunk * RR;

  const int wave = tid >> 6, lane = tid & 63;
  const int quad = lane >> 4, lidx = lane & 15;
  const int mtile = wave & 1;           // rows mtile*16 .. +15
  const int nbase = (wave >> 1) * 64;   // 4 n-tiles of 16
  const int utb = (wave >> 1) * 4;      // global u-tile base for this wave

  // per-lane A row pointer (as float4), row = s0 + mtile*16 + lidx
  const float4* arow4 = (const float4*)(values + ((size_t)b * NS + s0 + mtile * 16 + lidx) * ND);
  const uint4* wfl = w2f + lane;

  f32x4 acc[4] = {{0.f,0.f,0.f,0.f},{0.f,0.f,0.f,0.f},{0.f,0.f,0.f,0.f},{0.f,0.f,0.f,0.f}};

  #pragma unroll 2
  for (int kt = 0; kt < 16; ++kt) {
    float4 a0 = arow4[kt * 8 + quad * 2];
    float4 a1 = arow4[kt * 8 + quad * 2 + 1];
    FragCvt af;
    af.b[0] = (__bf16)a0.x; af.b[1] = (__bf16)a0.y;
    af.b[2] = (__bf16)a0.z; af.b[3] = (__bf16)a0.w;
    af.b[4] = (__bf16)a1.x; af.b[5] = (__bf16)a1.y;
    af.b[6] = (__bf16)a1.z; af.b[7] = (__bf16)a1.w;
    #pragma unroll
    for (int nt = 0; nt < 4; ++nt) {
      FragCvt bf; bf.u = *(const u16x8*)(wfl + (kt * 8 + utb + nt) * 64);
      acc[nt] = __builtin_amdgcn_mfma_f32_16x16x32_bf16(af.b, bf.b, acc[nt], 0, 0, 0);
    }
  }

  // ---- epilogue: tanh + dot with V; lane covers rows quad*4+r, cols nbase+nt*16+lidx ----
  float part[4] = {0.f, 0.f, 0.f, 0.f};
  #pragma unroll
  for (int nt = 0; nt < 4; ++nt) {
    const int col = nbase + nt * 16 + lidx;
    const float qv = qb[b * NU + col];
    const float vv = V[col];
    #pragma unroll
    for (int r = 0; r < 4; ++r)
      part[r] += fast_tanh(acc[nt][r] + qv) * vv;
  }
  // reduce across the 16 lanes of each quad (sum over n)
  #pragma unroll
  for (int m = 1; m <= 8; m <<= 1) {
    #pragma unroll
    for (int r = 0; r < 4; ++r) part[r] += __shfl_xor(part[r], m, 64);
  }
  if (lidx == 0) {
    #pragma unroll
    for (int r = 0; r < 4; ++r) sbuf[wave][quad * 4 + r] = part[r];
  }
  __syncthreads();

  if (tid < 32) {
    const int mt = tid >> 4, rr = tid & 15;
    float s = sbuf[mt][rr] + sbuf[mt + 2][rr];   // waves (0,2) cover mtile0; (1,3) mtile1
    float e = __expf(s + *bvp);                  // no max needed: |s| bounded by tanh*||V||
    wout[(size_t)b * NS + s0 + tid] = e;
    wlds[tid] = e;
    float es = e;
    #pragma unroll
    for (int m = 1; m <= 16; m <<= 1) es += __shfl_xor(es, m, 64);
    if (tid == 0) atomicAdd(Lacc + b, es);
  }
  __syncthreads();

  // ---- weighted context: c[d] = sum_r e_r * values[r][d], fp32 from L2-hot chunk ----
  const float* vb2 = values + ((size_t)b * NS + s0) * ND + tid * 2;
  float c0 = 0.f, c1 = 0.f;
  #pragma unroll 8
  for (int r = 0; r < RR; ++r) {
    const float w = wlds[r];
    const float2 v = *(const float2*)(vb2 + r * ND);
    c0 += w * v.x;
    c1 += w * v.y;
  }
  const int d0 = tid * 2;
  atomicAdd(Cacc + b * ND + d0, c0);
  atomicAdd(Cacc + b * ND + d0 + 1, c1);
}

// ---------------- finalize: divide by denom ----------------
__global__ void finalize(const float* __restrict__ Cacc, const float* __restrict__ Lacc,
                         float* __restrict__ out) {
  int idx = blockIdx.x * 256 + threadIdx.x;   // 147456 total
  if (idx < NB * ND) {
    int b = idx >> 9;
    out[idx] = Cacc[idx] / Lacc[b];
  } else {
    int j = idx - NB * ND;
    int b = j >> 12;
    out[idx] = out[idx] / Lacc[b];
  }
}

extern "C" void kernel_launch(void* const* d_in, const int* in_sizes, int n_in,
                              void* d_out, int out_size, void* d_ws, size_t ws_size,
                              hipStream_t stream) {
  const float* query  = (const float*)d_in[0];
  const float* values = (const float*)d_in[1];
  const float* W1     = (const float*)d_in[2];
  const float* b1     = (const float*)d_in[3];
  const float* W2     = (const float*)d_in[4];
  const float* b2     = (const float*)d_in[5];
  const float* V      = (const float*)d_in[6];
  const float* bv     = (const float*)d_in[7];
  float* out = (float*)d_out;

  char* ws = (char*)d_ws;
  float* Cacc = (float*)ws;                          // 65536 B
  float* Lacc = (float*)(ws + 65536);                // 128 B
  float* qb   = (float*)(ws + 66048);                // 16384 B
  uint4* w2f  = (uint4*)(ws + 66048 + 16384);        // 131072 B

  hipMemsetAsync(ws, 0, 66048 + 16384, stream);      // zero Cacc + Lacc + qb (atomic targets)

  prep_qb <<<NB * 16, 256, 0, stream>>>(query, W1, b1, b2, qb);
  prep_w2f<<<32, 256, 0, stream>>>(W2, w2f);
  fused_attn<<<NB * (NS / RR), 256, 0, stream>>>(values, qb, w2f, V, bv,
                                                 out + NB * ND, Cacc, Lacc);
  finalize<<<(NB * ND + NB * NS) / 256, 256, 0, stream>>>(Cacc, Lacc, out);
}

// Round 3
// 412.718 us; speedup vs baseline: 1.0733x; 1.0733x over previous
//
#include <hip/hip_runtime.h>
#include <math.h>

#define NB 32
#define NS 4096
#define ND 512
#define NU 128
#define RR 32          // rows of values per block
#define ASTR 520       // A LDS row stride (bf16 elems): 512 + 8 pad

typedef __bf16 bf16x8 __attribute__((ext_vector_type(8)));
typedef unsigned short u16x8 __attribute__((ext_vector_type(8)));
typedef float f32x4 __attribute__((ext_vector_type(4)));

union FragCvt { u16x8 u; bf16x8 b; };

__device__ inline unsigned short f2bf(float x) {
  union { float f; unsigned u; } v; v.f = x;
  return (unsigned short)((v.u + 0x7FFFu + ((v.u >> 16) & 1u)) >> 16);
}
__device__ inline float bf2f(unsigned int bits16) {  // low 16 bits are bf16
  union { unsigned u; float f; } v; v.u = bits16 << 16;
  return v.f;
}
__device__ inline float fast_tanh(float x) {
  x = fminf(9.f, fmaxf(-9.f, x));
  float e2 = __expf(2.f * x);
  return (e2 - 1.f) * __builtin_amdgcn_rcpf(e2 + 1.f);
}
// XOR swizzle for the B tile: spread 8 consecutive 128B-rows across 8 16B slots
__device__ inline int bswz(int byte) { return byte ^ (((byte >> 7) & 7) << 4); }

// ---------------- prep: qb[b][u] += partial(query@W1) + b1 + b2 (split-K, qb pre-zeroed) ----------------
__global__ void prep_qb(const float* __restrict__ q, const float* __restrict__ W1,
                        const float* __restrict__ b1, const float* __restrict__ b2,
                        float* __restrict__ qb) {
  const int bb = blockIdx.x >> 4;
  const int kc = blockIdx.x & 15;
  const int u  = threadIdx.x & 127;
  const int dh = threadIdx.x >> 7;
  const int d0 = kc * 32 + dh * 16;
  const float* qr = q + bb * ND + d0;
  const float* w  = W1 + (size_t)d0 * NU + u;
  float s = (kc == 0 && dh == 0) ? (b1[u] + b2[u]) : 0.f;
  #pragma unroll
  for (int j = 0; j < 16; ++j) s += qr[j] * w[j * NU];
  atomicAdd(qb + bb * NU + u, s);
}

// ---------------- prep: W2 -> k-tile-major bf16: w2s[kt][u][k'] (u-major rows of 32 k) ----------------
__global__ void prep_w2s(const float* __restrict__ W2, unsigned short* __restrict__ w2s) {
  const int idx = blockIdx.x * 256 + threadIdx.x;   // 65536
  const int u = idx & 127;
  const int r = idx >> 7;
  const int k = r & 31, kt = r >> 5;
  w2s[kt * 4096 + u * 32 + k] = f2bf(W2[(size_t)(kt * 32 + k) * NU + u]);
}

// ---------------- fused: proj -> tanh -> score -> exp -> partial softmax + context ----------------
// Line-traffic-minimal design: A staged once to LDS (bf16), B cooperatively restaged per kt
// through a double-buffered, XOR-swizzled LDS tile (one barrier per kt; prefetch issued after
// the barrier so it rides under the MFMA phase). Context pass reads the A LDS tile (0 lines).
__global__ __launch_bounds__(256, 3) void fused_attn(
    const float* __restrict__ values,
    const float* __restrict__ qb,            // [NB][NU]
    const unsigned short* __restrict__ w2s,  // [16][128][32] bf16 bits
    const float* __restrict__ V,             // [NU]
    const float* __restrict__ bvp,           // [1]
    float* __restrict__ wout,                // [NB][NS] unnormalized e^s
    float* __restrict__ Cacc,                // [NB][ND] partial context (ws, zeroed)
    float* __restrict__ Lacc)                // [NB] partial denom (ws, zeroed)
{
  __shared__ unsigned short Alds[RR * ASTR];     // 33,280 B
  __shared__ unsigned short Blds[2][128 * 32];   // 16,384 B
  __shared__ float sbuf[4][16];
  __shared__ float wlds[RR];

  const int tid = threadIdx.x;
  const int b = blockIdx.x >> 7;        // 128 chunks per batch
  const int chunk = blockIdx.x & 127;
  const int s0 = chunk * RR;

  // ---- issue B[kt=0] prefetch first (L2-resident w2s) ----
  const uint4* w2s4 = (const uint4*)w2s;    // 16B units; one kt tile = 512 uint4
  uint4 breg0 = w2s4[tid * 2];
  uint4 breg1 = w2s4[tid * 2 + 1];

  // ---- stage A: values[b][s0..s0+31][:] fp32 -> bf16 LDS; 8 loads in flight ----
  const float* vbase = values + ((size_t)b * NS + s0) * ND;
  #pragma unroll
  for (int ii = 0; ii < 16; ii += 8) {
    float4 v[8];
    #pragma unroll
    for (int j = 0; j < 8; ++j) {
      const int f = tid + 256 * (ii + j);            // float4 index in [0, 4096)
      v[j] = *(const float4*)(vbase + (f >> 7) * ND + (f & 127) * 4);
    }
    #pragma unroll
    for (int j = 0; j < 8; ++j) {
      const int f = tid + 256 * (ii + j);
      ushort4 pk;
      pk.x = f2bf(v[j].x); pk.y = f2bf(v[j].y); pk.z = f2bf(v[j].z); pk.w = f2bf(v[j].w);
      *(ushort4*)(&Alds[(f >> 7) * ASTR + (f & 127) * 4]) = pk;
    }
  }

  const int wave = tid >> 6, lane = tid & 63;
  const int quad = lane >> 4, lidx = lane & 15;
  const int mtile = wave & 1;           // rows mtile*16 .. +15
  const int nbase = (wave >> 1) * 64;   // 4 n-tiles of 16

  f32x4 acc[4] = {{0.f,0.f,0.f,0.f},{0.f,0.f,0.f,0.f},{0.f,0.f,0.f,0.f},{0.f,0.f,0.f,0.f}};
  const unsigned short* arow = &Alds[(mtile * 16 + lidx) * ASTR];

  for (int kt = 0; kt < 16; ++kt) {
    char* bdst = (char*)Blds[kt & 1];
    const int by0 = tid * 32;
    *(uint4*)(bdst + bswz(by0))      = breg0;   // vmcnt wait here consumes prefetch
    *(uint4*)(bdst + bswz(by0 + 16)) = breg1;
    __syncthreads();                            // drains lgkm: A writes (kt=0) + B writes
    if (kt < 15) {                              // prefetch next tile AFTER barrier:
      breg0 = w2s4[(kt + 1) * 512 + tid * 2];   // in flight across the MFMA phase,
      breg1 = w2s4[(kt + 1) * 512 + tid * 2 + 1]; // consumed at next iter's ds_write
    }
    FragCvt af; af.u = *(const u16x8*)(arow + kt * 32 + quad * 8);
    const char* bsrc = (const char*)Blds[kt & 1];
    #pragma unroll
    for (int nt = 0; nt < 4; ++nt) {
      const int bb2 = (nbase + nt * 16 + lidx) * 64 + quad * 16;
      FragCvt bf; bf.u = *(const u16x8*)(bsrc + bswz(bb2));
      acc[nt] = __builtin_amdgcn_mfma_f32_16x16x32_bf16(af.b, bf.b, acc[nt], 0, 0, 0);
    }
    // no tail barrier needed: double-buffered (kt+2's write is fenced by barrier kt+1)
  }

  // ---- epilogue: tanh + dot with V; lane covers rows quad*4+r, cols nbase+nt*16+lidx ----
  float part[4] = {0.f, 0.f, 0.f, 0.f};
  #pragma unroll
  for (int nt = 0; nt < 4; ++nt) {
    const int col = nbase + nt * 16 + lidx;
    const float qv = qb[b * NU + col];
    const float vv = V[col];
    #pragma unroll
    for (int r = 0; r < 4; ++r)
      part[r] += fast_tanh(acc[nt][r] + qv) * vv;
  }
  #pragma unroll
  for (int m = 1; m <= 8; m <<= 1) {
    #pragma unroll
    for (int r = 0; r < 4; ++r) part[r] += __shfl_xor(part[r], m, 64);
  }
  if (lidx == 0) {
    #pragma unroll
    for (int r = 0; r < 4; ++r) sbuf[wave][quad * 4 + r] = part[r];
  }
  __syncthreads();

  if (tid < 32) {
    const int mt = tid >> 4, rr = tid & 15;
    float s = sbuf[mt][rr] + sbuf[mt + 2][rr];   // waves (0,2) cover mtile0; (1,3) mtile1
    float e = __expf(s + *bvp);                  // no max needed: |s| bounded by tanh*||V||
    wout[(size_t)b * NS + s0 + tid] = e;
    wlds[tid] = e;
    float es = e;
    #pragma unroll
    for (int m = 1; m <= 16; m <<= 1) es += __shfl_xor(es, m, 64);
    if (tid == 0) atomicAdd(Lacc + b, es);
  }
  __syncthreads();

  // ---- weighted context from the A LDS tile (bf16): zero extra global lines ----
  const int d0 = tid * 2;
  float c0 = 0.f, c1 = 0.f;
  #pragma unroll 8
  for (int r = 0; r < RR; ++r) {
    const float w = wlds[r];
    const unsigned int pk = *(const unsigned int*)(&Alds[r * ASTR + d0]);
    c0 += w * bf2f(pk & 0xFFFFu);
    c1 += w * bf2f(pk >> 16);
  }
  atomicAdd(Cacc + b * ND + d0, c0);
  atomicAdd(Cacc + b * ND + d0 + 1, c1);
}

// ---------------- finalize: divide by denom ----------------
__global__ void finalize(const float* __restrict__ Cacc, const float* __restrict__ Lacc,
                         float* __restrict__ out) {
  int idx = blockIdx.x * 256 + threadIdx.x;   // 147456 total
  if (idx < NB * ND) {
    int b = idx >> 9;
    out[idx] = Cacc[idx] / Lacc[b];
  } else {
    int j = idx - NB * ND;
    int b = j >> 12;
    out[idx] = out[idx] / Lacc[b];
  }
}

extern "C" void kernel_launch(void* const* d_in, const int* in_sizes, int n_in,
                              void* d_out, int out_size, void* d_ws, size_t ws_size,
                              hipStream_t stream) {
  const float* query  = (const float*)d_in[0];
  const float* values = (const float*)d_in[1];
  const float* W1     = (const float*)d_in[2];
  const float* b1     = (const float*)d_in[3];
  const float* W2     = (const float*)d_in[4];
  const float* b2     = (const float*)d_in[5];
  const float* V      = (const float*)d_in[6];
  const float* bv     = (const float*)d_in[7];
  float* out = (float*)d_out;

  char* ws = (char*)d_ws;
  float* Cacc = (float*)ws;                               // 65536 B
  float* Lacc = (float*)(ws + 65536);                     // 128 B
  float* qb   = (float*)(ws + 66048);                     // 16384 B
  unsigned short* w2s = (unsigned short*)(ws + 66048 + 16384);  // 131072 B

  hipMemsetAsync(ws, 0, 66048 + 16384, stream);           // zero Cacc + Lacc + qb

  prep_qb <<<NB * 16, 256, 0, stream>>>(query, W1, b1, b2, qb);
  prep_w2s<<<256, 256, 0, stream>>>(W2, w2s);
  fused_attn<<<NB * (NS / RR), 256, 0, stream>>>(values, qb, w2s, V, bv,
                                                 out + NB * ND, Cacc, Lacc);
  finalize<<<(NB * ND + NB * NS) / 256, 256, 0, stream>>>(Cacc, Lacc, out);
}